// Round 6
// baseline (273.619 us; speedup 1.0000x reference)
//
#include <hip/hip_runtime.h>
#include <math.h>

#define B_ 8
#define C_ 128
#define N_ 16384
#define SCALE_ 0.17677669529663687f
#define EPS_ 1e-5f

#define KV_STRIDE 36    // k/v tiles [128][36] fp32 (ctx kernel)
#define XU_STRIDE 68    // packed f16-pair (uint) tile stride
#define REC_ 4224       // per-block record: 4096 P + 128 S

typedef _Float16 half8 __attribute__((ext_vector_type(8)));
typedef float floatx4 __attribute__((ext_vector_type(4)));

static __device__ inline unsigned short f16bits(float v) {
  _Float16 h = (_Float16)v;
  return __builtin_bit_cast(unsigned short, h);
}

// pack two floats into one hi-pair uint and one lo-pair uint (split-f16)
static __device__ inline void pack2(float a0, float a1,
                                    unsigned int& hp, unsigned int& lp) {
  _Float16 h0 = (_Float16)a0;
  _Float16 h1 = (_Float16)a1;
  float l0f = (a0 - (float)h0) * 2048.0f;
  float l1f = (a1 - (float)h1) * 2048.0f;
  hp = ((unsigned int)__builtin_bit_cast(unsigned short, h1) << 16) |
       (unsigned int)__builtin_bit_cast(unsigned short, h0);
  lp = ((unsigned int)f16bits(l1f) << 16) | (unsigned int)f16bits(l0f);
}

static __device__ inline void split8(const float* p, half8& hi, half8& lo) {
  float4 f0 = *(const float4*)p;
  float4 f1 = *(const float4*)(p + 4);
  float fv[8] = {f0.x, f0.y, f0.z, f0.w, f1.x, f1.y, f1.z, f1.w};
#pragma unroll
  for (int j = 0; j < 8; ++j) {
    _Float16 hj = (_Float16)fv[j];
    hi[j] = hj;
    lo[j] = (_Float16)((fv[j] - (float)hj) * 2048.0f);
  }
}

// ---------------------------------------------------------------------------
// Kernel 1 (UNCHANGED, proven 82 us in R1): k/v GEMM via split-f16 MFMA,
// exp(k); P accumulated via MFMA across chunks; 2 barriers/chunk.
// grid = B_ * bpb, block = 256
// ---------------------------------------------------------------------------
__global__ __launch_bounds__(256, 2) void lin_attn_ctx(
    const float* __restrict__ x, const float* __restrict__ wqkv,
    float* __restrict__ Ws)
{
  __shared__ __align__(16) unsigned int xhiu[32 * XU_STRIDE];
  __shared__ __align__(16) unsigned int xlou[32 * XU_STRIDE];
  __shared__ __align__(16) float ks[128 * KV_STRIDE];
  __shared__ __align__(16) float vs[128 * KV_STRIDE];

  const int t = threadIdx.x;
  const int bpb = gridDim.x / B_;
  const int b = blockIdx.x / bpb;
  const int blk = blockIdx.x - b * bpb;
  const int nchunks = 512 / bpb;
  const int pbase = blk * (nchunks << 5);

  const int lane = t & 63;
  const int wave = t >> 6;
  const int l15 = lane & 15;
  const int quad = lane >> 4;

  half8 ahi[4][4], alo[4][4];
#pragma unroll
  for (int r = 0; r < 4; ++r) {
#pragma unroll
    for (int s = 0; s < 4; ++s) {
      const int m = (wave << 6) + (r << 4) + l15;
      split8(wqkv + (size_t)(128 + m) * C_ + (s << 5) + (quad << 3),
             ahi[r][s], alo[r][s]);
    }
  }

  floatx4 pacc1[2][2], pacc2[2][2];
#pragma unroll
  for (int i = 0; i < 2; ++i)
#pragma unroll
    for (int j = 0; j < 2; ++j) {
      pacc1[i][j] = (floatx4){0.f, 0.f, 0.f, 0.f};
      pacc2[i][j] = (floatx4){0.f, 0.f, 0.f, 0.f};
    }
  float sacc[16];
#pragma unroll
  for (int u = 0; u < 16; ++u) sacc[u] = 0.f;

  const float* xb = x + ((size_t)b * C_) * N_;
  const int kp0 = t >> 3;
  const int pq0 = (t & 7) << 2;

  float4 fa0, fa1, fb0, fb1;
  {
    const float* p = xb + pbase + pq0;
    fa0 = *(const float4*)(p + (size_t)(2 * kp0) * N_);
    fa1 = *(const float4*)(p + (size_t)(2 * kp0 + 1) * N_);
    fb0 = *(const float4*)(p + (size_t)(2 * kp0 + 64) * N_);
    fb1 = *(const float4*)(p + (size_t)(2 * kp0 + 65) * N_);
  }

  for (int c4 = 0; c4 < nchunks; ++c4) {
    __syncthreads();   // A

    half8 eh[2], el[2], vh[2], vl[2];
    if (c4 > 0) {
#pragma unroll
      for (int tt = 0; tt < 2; ++tt) {
        split8(&ks[(wave * 32 + tt * 16 + l15) * KV_STRIDE + (quad << 3)], eh[tt], el[tt]);
        split8(&vs[(wave * 32 + tt * 16 + l15) * KV_STRIDE + (quad << 3)], vh[tt], vl[tt]);
      }
    }

    {
      float a0[4] = {fa0.x, fa0.y, fa0.z, fa0.w};
      float a1[4] = {fa1.x, fa1.y, fa1.z, fa1.w};
      float c0[4] = {fb0.x, fb0.y, fb0.z, fb0.w};
      float c1[4] = {fb1.x, fb1.y, fb1.z, fb1.w};
#pragma unroll
      for (int j = 0; j < 4; ++j) {
        unsigned int hp, lp;
        pack2(a0[j], a1[j], hp, lp);
        xhiu[(pq0 + j) * XU_STRIDE + kp0] = hp;
        xlou[(pq0 + j) * XU_STRIDE + kp0] = lp;
        pack2(c0[j], c1[j], hp, lp);
        xhiu[(pq0 + j) * XU_STRIDE + kp0 + 32] = hp;
        xlou[(pq0 + j) * XU_STRIDE + kp0 + 32] = lp;
      }
    }

    if (c4 > 0) {
      __builtin_amdgcn_s_setprio(1);
#pragma unroll
      for (int at = 0; at < 2; ++at)
#pragma unroll
        for (int bt = 0; bt < 2; ++bt) {
          pacc1[at][bt] = __builtin_amdgcn_mfma_f32_16x16x32_f16(eh[at], vh[bt], pacc1[at][bt], 0, 0, 0);
          pacc2[at][bt] = __builtin_amdgcn_mfma_f32_16x16x32_f16(eh[at], vl[bt], pacc2[at][bt], 0, 0, 0);
          pacc2[at][bt] = __builtin_amdgcn_mfma_f32_16x16x32_f16(el[at], vh[bt], pacc2[at][bt], 0, 0, 0);
        }
      __builtin_amdgcn_s_setprio(0);
    }

    __syncthreads();   // B

    if (c4 + 1 < nchunks) {
      const float* p = xb + pbase + ((c4 + 1) << 5) + pq0;
      fa0 = *(const float4*)(p + (size_t)(2 * kp0) * N_);
      fa1 = *(const float4*)(p + (size_t)(2 * kp0 + 1) * N_);
      fb0 = *(const float4*)(p + (size_t)(2 * kp0 + 64) * N_);
      fb1 = *(const float4*)(p + (size_t)(2 * kp0 + 65) * N_);
    }

    floatx4 acc1[4][2], acc2[4][2];
#pragma unroll
    for (int r = 0; r < 4; ++r)
#pragma unroll
      for (int c = 0; c < 2; ++c) {
        acc1[r][c] = (floatx4){0.f, 0.f, 0.f, 0.f};
        acc2[r][c] = (floatx4){0.f, 0.f, 0.f, 0.f};
      }
    __builtin_amdgcn_s_setprio(1);
#pragma unroll
    for (int s = 0; s < 4; ++s) {
#pragma unroll
      for (int c = 0; c < 2; ++c) {
        int off = ((c << 4) + l15) * XU_STRIDE + (s << 4) + (quad << 2);
        half8 bh = __builtin_bit_cast(half8, *(const uint4*)&xhiu[off]);
        half8 bl = __builtin_bit_cast(half8, *(const uint4*)&xlou[off]);
#pragma unroll
        for (int r = 0; r < 4; ++r) {
          acc1[r][c] = __builtin_amdgcn_mfma_f32_16x16x32_f16(ahi[r][s], bh, acc1[r][c], 0, 0, 0);
          acc2[r][c] = __builtin_amdgcn_mfma_f32_16x16x32_f16(ahi[r][s], bl, acc2[r][c], 0, 0, 0);
          acc2[r][c] = __builtin_amdgcn_mfma_f32_16x16x32_f16(alo[r][s], bh, acc2[r][c], 0, 0, 0);
        }
      }
    }
    __builtin_amdgcn_s_setprio(0);

    if (wave < 2) {
#pragma unroll
      for (int r = 0; r < 4; ++r)
#pragma unroll
        for (int c = 0; c < 2; ++c) {
          int px = (c << 4) + l15;
#pragma unroll
          for (int reg = 0; reg < 4; ++reg) {
            float val = acc1[r][c][reg] + acc2[r][c][reg] * (1.0f / 2048.0f);
            int row = (wave << 6) + (r << 4) + (quad << 2) + reg;
            float e = __expf(val);
            ks[row * KV_STRIDE + px] = e;
            sacc[r * 4 + reg] += e;
          }
        }
    } else {
#pragma unroll
      for (int r = 0; r < 4; ++r)
#pragma unroll
        for (int c = 0; c < 2; ++c) {
          int px = (c << 4) + l15;
#pragma unroll
          for (int reg = 0; reg < 4; ++reg) {
            float val = acc1[r][c][reg] + acc2[r][c][reg] * (1.0f / 2048.0f);
            int row = (wave << 6) + (r << 4) + (quad << 2) + reg - 128;
            vs[row * KV_STRIDE + px] = val;
          }
        }
    }
  }

  __syncthreads();
  {
    half8 eh[2], el[2], vh[2], vl[2];
#pragma unroll
    for (int tt = 0; tt < 2; ++tt) {
      split8(&ks[(wave * 32 + tt * 16 + l15) * KV_STRIDE + (quad << 3)], eh[tt], el[tt]);
      split8(&vs[(wave * 32 + tt * 16 + l15) * KV_STRIDE + (quad << 3)], vh[tt], vl[tt]);
    }
#pragma unroll
    for (int at = 0; at < 2; ++at)
#pragma unroll
      for (int bt = 0; bt < 2; ++bt) {
        pacc1[at][bt] = __builtin_amdgcn_mfma_f32_16x16x32_f16(eh[at], vh[bt], pacc1[at][bt], 0, 0, 0);
        pacc2[at][bt] = __builtin_amdgcn_mfma_f32_16x16x32_f16(eh[at], vl[bt], pacc2[at][bt], 0, 0, 0);
        pacc2[at][bt] = __builtin_amdgcn_mfma_f32_16x16x32_f16(el[at], vh[bt], pacc2[at][bt], 0, 0, 0);
      }
  }

  {
    float* rec = Ws + (size_t)blockIdx.x * REC_;
#pragma unroll
    for (int at = 0; at < 2; ++at)
#pragma unroll
      for (int bt = 0; bt < 2; ++bt)
#pragma unroll
        for (int reg = 0; reg < 4; ++reg) {
          int dk = at * 16 + (quad << 2) + reg;
          int dv = bt * 16 + l15;
          rec[((wave * 32 + dk) << 5) + dv] =
              pacc1[at][bt][reg] + pacc2[at][bt][reg] * (1.0f / 2048.0f);
        }
    if (wave < 2) {
#pragma unroll
      for (int u = 0; u < 16; ++u) {
        float s = sacc[u];
        s += __shfl_xor(s, 1);
        s += __shfl_xor(s, 2);
        s += __shfl_xor(s, 4);
        s += __shfl_xor(s, 8);
        sacc[u] = s;
      }
      if (l15 == 0) {
#pragma unroll
        for (int r = 0; r < 4; ++r)
#pragma unroll
          for (int reg = 0; reg < 4; ++reg)
            rec[4096 + (wave << 6) + (r << 4) + (quad << 2) + reg] = sacc[r * 4 + reg];
      }
    }
  }
}

// ---------------------------------------------------------------------------
// Fused reduce+gmat (UNCHANGED): grid = B_*32, block = 256
// ---------------------------------------------------------------------------
__global__ void lin_attn_redg(const float* __restrict__ Ws, int slots,
                              const float* __restrict__ wout,
                              float* __restrict__ G)
{
  __shared__ float p2[256];
  __shared__ float cx[128];
  __shared__ float ss[4];

  const int t = threadIdx.x;
  const int b = blockIdx.x >> 5;
  const int seg = blockIdx.x & 31;
  const int R0 = seg << 2;
  const int hs = slots >> 1;

  {
    const int e = t & 127;
    const int half = t >> 7;
    const float* src = Ws + ((size_t)b * slots + (size_t)half * hs) * REC_ +
                       R0 * 32 + e;
    float s = 0.f;
    for (int k = 0; k < hs; ++k) s += src[(size_t)k * REC_];
    p2[half * 128 + e] = s;
  }
  {
    const int row4 = t >> 6;
    const int lane = t & 63;
    float sv = (lane < slots)
             ? Ws[((size_t)b * slots + lane) * REC_ + 4096 + R0 + row4] : 0.f;
    sv += __shfl_xor(sv, 1);
    sv += __shfl_xor(sv, 2);
    sv += __shfl_xor(sv, 4);
    sv += __shfl_xor(sv, 8);
    sv += __shfl_xor(sv, 16);
    sv += __shfl_xor(sv, 32);
    if (lane == 0) ss[row4] = sv;
  }
  __syncthreads();
  if (t < 128) {
    cx[t] = (p2[t] + p2[128 + t]) / (ss[t >> 5] * 16384.f);
  }
  __syncthreads();
  {
    const int o = t >> 1;
    const int pr = t & 1;
#pragma unroll
    for (int p = 0; p < 2; ++p) {
      const int row4 = pr * 2 + p;
      const int grow = R0 + row4;
      const int h = grow >> 5;
      const float* wrow = wout + (size_t)o * 128 + h * 32;
      const float* crow = &cx[row4 * 32];
      float s = 0.f;
#pragma unroll
      for (int q = 0; q < 8; ++q) {
        float4 w4 = *(const float4*)&wrow[q * 4];
        float4 c4 = *(const float4*)&crow[q * 4];
        s += w4.x * c4.x + w4.y * c4.y + w4.z * c4.z + w4.w * c4.w;
      }
      G[(size_t)b * 16384 + (size_t)o * 128 + grow] = s * SCALE_;
    }
  }
}

// ---------------------------------------------------------------------------
// Kernel 2 (2 barriers/chunk, deferred LayerNorm): chunk i's LN-final+store
// happens in iteration i+1's alpha window (y kept in regs, red partials
// written without a trailing barrier — next alpha makes them visible).
// iter i: prefetch(i+1) | qGEMM(i) | softmax(i) | [a] LNfinal(i-1)+store,
//         emit(i), stage(i+1) | [b] yGEMM(i) | yv=y+bias | LNpartials(i).
// grid = B_*bpb, block = 256
// ---------------------------------------------------------------------------
__global__ __launch_bounds__(256, 2) void lin_attn_out(
    const float* __restrict__ x, const float* __restrict__ wqkv,
    const float* __restrict__ G, const float* __restrict__ bout,
    const float* __restrict__ alpha, const float* __restrict__ beta,
    float* __restrict__ out)
{
  __shared__ __align__(16) unsigned int xh[2][32 * XU_STRIDE];
  __shared__ __align__(16) unsigned int xl[2][32 * XU_STRIDE];
  __shared__ __align__(16) unsigned int qhiu[32 * XU_STRIDE];
  __shared__ __align__(16) unsigned int qlou[32 * XU_STRIDE];
  __shared__ float red_s[128];
  __shared__ float red_q[128];

  const int t = threadIdx.x;
  const int bpb = gridDim.x / B_;
  const int b = blockIdx.x / bpb;
  const int blk = blockIdx.x - b * bpb;
  const int nchunks = 512 / bpb;
  const int pbase = blk * (nchunks << 5);

  const int lane = t & 63;
  const int wave = t >> 6;
  const int l15 = lane & 15;
  const int quad = lane >> 4;

  half8 qhiA[2][4], qloA[2][4], ghiA[2][4], gloA[2][4];
#pragma unroll
  for (int r = 0; r < 2; ++r) {
#pragma unroll
    for (int s = 0; s < 4; ++s) {
      const int m = (wave << 5) + (r << 4) + l15;
      split8(wqkv + (size_t)m * C_ + (s << 5) + (quad << 3), qhiA[r][s], qloA[r][s]);
      split8(G + (size_t)b * 16384 + (size_t)m * 128 + (s << 5) + (quad << 3),
             ghiA[r][s], gloA[r][s]);
    }
  }

  float bch[8], ach[8], bech[8];
#pragma unroll
  for (int r = 0; r < 2; ++r)
#pragma unroll
    for (int reg = 0; reg < 4; ++reg) {
      int ch = (wave << 5) + (r << 4) + (quad << 2) + reg;
      bch[r * 4 + reg] = bout[ch];
      ach[r * 4 + reg] = alpha[ch];
      bech[r * 4 + reg] = beta[ch];
    }

  const float* xb = x + ((size_t)b * C_) * N_;
  const int kp0 = t >> 3;
  const int pq0 = (t & 7) << 2;
  float4 fa0, fa1, fb0, fb1;

  // prologue: prefetch + stage chunk 0 into buffer 0
  {
    const float* p = xb + pbase + pq0;
    fa0 = *(const float4*)(p + (size_t)(2 * kp0) * N_);
    fa1 = *(const float4*)(p + (size_t)(2 * kp0 + 1) * N_);
    fb0 = *(const float4*)(p + (size_t)(2 * kp0 + 64) * N_);
    fb1 = *(const float4*)(p + (size_t)(2 * kp0 + 65) * N_);
    float a0[4] = {fa0.x, fa0.y, fa0.z, fa0.w};
    float a1[4] = {fa1.x, fa1.y, fa1.z, fa1.w};
    float c0[4] = {fb0.x, fb0.y, fb0.z, fb0.w};
    float c1[4] = {fb1.x, fb1.y, fb1.z, fb1.w};
#pragma unroll
    for (int j = 0; j < 4; ++j) {
      unsigned int hp, lp;
      pack2(a0[j], a1[j], hp, lp);
      xh[0][(pq0 + j) * XU_STRIDE + kp0] = hp;
      xl[0][(pq0 + j) * XU_STRIDE + kp0] = lp;
      pack2(c0[j], c1[j], hp, lp);
      xh[0][(pq0 + j) * XU_STRIDE + kp0 + 32] = hp;
      xl[0][(pq0 + j) * XU_STRIDE + kp0 + 32] = lp;
    }
  }
  __syncthreads();

  float yv[2][8];   // chunk i's y+bias, consumed at LN-final in iter i+1

  for (int c4 = 0; c4 < nchunks; ++c4) {
    const int cur = c4 & 1;
    const int nxt = cur ^ 1;

    // prefetch next chunk (consumed at stage after barrier alpha)
    if (c4 + 1 < nchunks) {
      const float* p = xb + pbase + ((c4 + 1) << 5) + pq0;
      fa0 = *(const float4*)(p + (size_t)(2 * kp0) * N_);
      fa1 = *(const float4*)(p + (size_t)(2 * kp0 + 1) * N_);
      fb0 = *(const float4*)(p + (size_t)(2 * kp0 + 64) * N_);
      fb1 = *(const float4*)(p + (size_t)(2 * kp0 + 65) * N_);
    }

    // ---- q GEMM from xh[cur] ----
    floatx4 a1a[2][2], a2a[2][2];
#pragma unroll
    for (int r = 0; r < 2; ++r)
#pragma unroll
      for (int c = 0; c < 2; ++c) {
        a1a[r][c] = (floatx4){0.f, 0.f, 0.f, 0.f};
        a2a[r][c] = (floatx4){0.f, 0.f, 0.f, 0.f};
      }
    __builtin_amdgcn_s_setprio(1);
#pragma unroll
    for (int s = 0; s < 4; ++s) {
#pragma unroll
      for (int c = 0; c < 2; ++c) {
        int off = ((c << 4) + l15) * XU_STRIDE + (s << 4) + (quad << 2);
        half8 bh = __builtin_bit_cast(half8, *(const uint4*)&xh[cur][off]);
        half8 bl = __builtin_bit_cast(half8, *(const uint4*)&xl[cur][off]);
#pragma unroll
        for (int r = 0; r < 2; ++r) {
          a1a[r][c] = __builtin_amdgcn_mfma_f32_16x16x32_f16(qhiA[r][s], bh, a1a[r][c], 0, 0, 0);
          a2a[r][c] = __builtin_amdgcn_mfma_f32_16x16x32_f16(qhiA[r][s], bl, a2a[r][c], 0, 0, 0);
          a2a[r][c] = __builtin_amdgcn_mfma_f32_16x16x32_f16(qloA[r][s], bh, a2a[r][c], 0, 0, 0);
        }
      }
    }
    __builtin_amdgcn_s_setprio(0);

    // ---- in-register head softmax -> normalized e values in registers ----
    float eq[2][8];
#pragma unroll
    for (int c = 0; c < 2; ++c) {
      float qv[8];
#pragma unroll
      for (int r = 0; r < 2; ++r)
#pragma unroll
        for (int reg = 0; reg < 4; ++reg)
          qv[r * 4 + reg] = a1a[r][c][reg] + a2a[r][c][reg] * (1.0f / 2048.0f);
      float mx = fmaxf(fmaxf(fmaxf(qv[0], qv[1]), fmaxf(qv[2], qv[3])),
                       fmaxf(fmaxf(qv[4], qv[5]), fmaxf(qv[6], qv[7])));
      mx = fmaxf(mx, __shfl_xor(mx, 16));
      mx = fmaxf(mx, __shfl_xor(mx, 32));
      float ss = 0.f;
#pragma unroll
      for (int j = 0; j < 8; ++j) { eq[c][j] = __expf(qv[j] - mx); ss += eq[c][j]; }
      ss += __shfl_xor(ss, 16);
      ss += __shfl_xor(ss, 32);
      float inv = 1.0f / ss;   // scale folded into G
#pragma unroll
      for (int j = 0; j < 8; ++j) eq[c][j] *= inv;
    }
    __syncthreads();   // alpha: orders emit(i) vs yGEMM(i-1) qhiu reads;
                       //        red writes(i-1) -> LN-final reads(i-1)

    // ---- deferred LN-final + store for PREVIOUS chunk ----
    if (c4 > 0) {
      float* ob = out + ((size_t)b * C_) * N_ + pbase + ((c4 - 1) << 5);
#pragma unroll
      for (int c = 0; c < 2; ++c) {
        int px = (c << 4) + l15;
        float ts = red_s[px] + red_s[32 + px] + red_s[64 + px] + red_s[96 + px];
        float tq = red_q[px] + red_q[32 + px] + red_q[64 + px] + red_q[96 + px];
        float mean = ts * (1.f / 128.f);
        float var = tq * (1.f / 128.f) - mean * mean;
        float rstd = 1.f / sqrtf(var + EPS_);
#pragma unroll
        for (int r = 0; r < 2; ++r)
#pragma unroll
          for (int reg = 0; reg < 4; ++reg) {
            int ch = (wave << 5) + (r << 4) + (quad << 2) + reg;
            ob[(size_t)ch * N_ + px] =
                (yv[c][r * 4 + reg] - mean) * rstd * ach[r * 4 + reg] + bech[r * 4 + reg];
          }
      }
    }

    // ---- emit qhat ----
#pragma unroll
    for (int c = 0; c < 2; ++c) {
      int px = (c << 4) + l15;
#pragma unroll
      for (int r = 0; r < 2; ++r) {
        unsigned int h0, l0, h1, l1;
        pack2(eq[c][r * 4 + 0], eq[c][r * 4 + 1], h0, l0);
        pack2(eq[c][r * 4 + 2], eq[c][r * 4 + 3], h1, l1);
        int kp = (wave << 4) + (r << 3) + (quad << 1);
        uint2 hu; hu.x = h0; hu.y = h1;
        uint2 lu; lu.x = l0; lu.y = l1;
        *(uint2*)&qhiu[px * XU_STRIDE + kp] = hu;
        *(uint2*)&qlou[px * XU_STRIDE + kp] = lu;
      }
    }
    // ---- stage next chunk into xh[nxt] ----
    if (c4 + 1 < nchunks) {
      float a0[4] = {fa0.x, fa0.y, fa0.z, fa0.w};
      float a1[4] = {fa1.x, fa1.y, fa1.z, fa1.w};
      float c0[4] = {fb0.x, fb0.y, fb0.z, fb0.w};
      float c1[4] = {fb1.x, fb1.y, fb1.z, fb1.w};
#pragma unroll
      for (int j = 0; j < 4; ++j) {
        unsigned int hp, lp;
        pack2(a0[j], a1[j], hp, lp);
        xh[nxt][(pq0 + j) * XU_STRIDE + kp0] = hp;
        xl[nxt][(pq0 + j) * XU_STRIDE + kp0] = lp;
        pack2(c0[j], c1[j], hp, lp);
        xh[nxt][(pq0 + j) * XU_STRIDE + kp0 + 32] = hp;
        xl[nxt][(pq0 + j) * XU_STRIDE + kp0 + 32] = lp;
      }
    }
    __syncthreads();   // beta: emit visible for yGEMM(i); stage visible for
                       //       qGEMM(i+1); red reads(i-1) -> red writes(i)

    // ---- y GEMM: y = G * qhat ----
#pragma unroll
    for (int r = 0; r < 2; ++r)
#pragma unroll
      for (int c = 0; c < 2; ++c) {
        a1a[r][c] = (floatx4){0.f, 0.f, 0.f, 0.f};
        a2a[r][c] = (floatx4){0.f, 0.f, 0.f, 0.f};
      }
    __builtin_amdgcn_s_setprio(1);
#pragma unroll
    for (int s = 0; s < 4; ++s) {
#pragma unroll
      for (int c = 0; c < 2; ++c) {
        int off = ((c << 4) + l15) * XU_STRIDE + (s << 4) + (quad << 2);
        half8 bh = __builtin_bit_cast(half8, *(const uint4*)&qhiu[off]);
        half8 bl = __builtin_bit_cast(half8, *(const uint4*)&qlou[off]);
#pragma unroll
        for (int r = 0; r < 2; ++r) {
          a1a[r][c] = __builtin_amdgcn_mfma_f32_16x16x32_f16(ghiA[r][s], bh, a1a[r][c], 0, 0, 0);
          a2a[r][c] = __builtin_amdgcn_mfma_f32_16x16x32_f16(ghiA[r][s], bl, a2a[r][c], 0, 0, 0);
          a2a[r][c] = __builtin_amdgcn_mfma_f32_16x16x32_f16(gloA[r][s], bh, a2a[r][c], 0, 0, 0);
        }
      }
    }
    __builtin_amdgcn_s_setprio(0);

    // ---- y + bias into yv; LayerNorm partials (no trailing barrier) ----
#pragma unroll
    for (int c = 0; c < 2; ++c) {
      float sm = 0.f, sq = 0.f;
#pragma unroll
      for (int r = 0; r < 2; ++r)
#pragma unroll
        for (int reg = 0; reg < 4; ++reg) {
          float v = a1a[r][c][reg] + a2a[r][c][reg] * (1.0f / 2048.0f) + bch[r * 4 + reg];
          yv[c][r * 4 + reg] = v;
          sm += v;
          sq += v * v;
        }
      sm += __shfl_xor(sm, 16);  sq += __shfl_xor(sq, 16);
      sm += __shfl_xor(sm, 32);  sq += __shfl_xor(sq, 32);
      if (quad == 0) {
        red_s[(wave << 5) + (c << 4) + l15] = sm;
        red_q[(wave << 5) + (c << 4) + l15] = sq;
      }
    }
  }

  // ---- epilogue: LN-final + store for the last chunk ----
  __syncthreads();
  {
    float* ob = out + ((size_t)b * C_) * N_ + pbase + ((nchunks - 1) << 5);
#pragma unroll
    for (int c = 0; c < 2; ++c) {
      int px = (c << 4) + l15;
      float ts = red_s[px] + red_s[32 + px] + red_s[64 + px] + red_s[96 + px];
      float tq = red_q[px] + red_q[32 + px] + red_q[64 + px] + red_q[96 + px];
      float mean = ts * (1.f / 128.f);
      float var = tq * (1.f / 128.f) - mean * mean;
      float rstd = 1.f / sqrtf(var + EPS_);
#pragma unroll
      for (int r = 0; r < 2; ++r)
#pragma unroll
        for (int reg = 0; reg < 4; ++reg) {
          int ch = (wave << 5) + (r << 4) + (quad << 2) + reg;
          ob[(size_t)ch * N_ + px] =
              (yv[c][r * 4 + reg] - mean) * rstd * ach[r * 4 + reg] + bech[r * 4 + reg];
        }
    }
  }
}

extern "C" void kernel_launch(void* const* d_in, const int* in_sizes, int n_in,
                              void* d_out, int out_size, void* d_ws, size_t ws_size,
                              hipStream_t stream) {
  const float* x     = (const float*)d_in[0];
  const float* wqkv  = (const float*)d_in[1];
  const float* wout  = (const float*)d_in[2];
  const float* bout  = (const float*)d_in[3];
  const float* alpha = (const float*)d_in[4];
  const float* beta  = (const float*)d_in[5];
  float* outp = (float*)d_out;

  // workspace layout: G | (reserved) | records
  float* G  = (float*)d_ws;                          // [B][128][128]
  float* Ws = G + (size_t)B_ * 16384 + B_ * 4096 + B_ * 128;

  size_t need64 = ((size_t)B_ * 16384 + B_ * 4096 + B_ * 128 +
                   (size_t)B_ * 64 * REC_) * sizeof(float);
  int bpb_ctx = (ws_size >= need64) ? 64 : 32;

  lin_attn_ctx<<<dim3(B_ * bpb_ctx), dim3(256), 0, stream>>>(x, wqkv, Ws);
  lin_attn_redg<<<dim3(B_ * 32), dim3(256), 0, stream>>>(Ws, bpb_ctx, wout, G);
  lin_attn_out<<<dim3(B_ * 64), dim3(256), 0, stream>>>(x, wqkv, G, bout,
                                                        alpha, beta, outp);
}

// Round 8
// 196.867 us; speedup vs baseline: 1.3899x; 1.3899x over previous
//
#include <hip/hip_runtime.h>
#include <math.h>

#define B_ 8
#define C_ 128
#define N_ 16384
#define SCALE_ 0.17677669529663687f
#define EPS_ 1e-5f

#define KV_STRIDE 36    // k/v tiles [128][36] fp32 (ctx kernel)
#define XU_STRIDE 68    // packed f16-pair (uint) tile stride
#define REC_ 4224       // per-block record: 4096 P + 128 S

typedef _Float16 half8 __attribute__((ext_vector_type(8)));
typedef float floatx4 __attribute__((ext_vector_type(4)));

static __device__ inline unsigned short f16bits(float v) {
  _Float16 h = (_Float16)v;
  return __builtin_bit_cast(unsigned short, h);
}

// pack two floats into one hi-pair uint and one lo-pair uint (split-f16)
static __device__ inline void pack2(float a0, float a1,
                                    unsigned int& hp, unsigned int& lp) {
  _Float16 h0 = (_Float16)a0;
  _Float16 h1 = (_Float16)a1;
  float l0f = (a0 - (float)h0) * 2048.0f;
  float l1f = (a1 - (float)h1) * 2048.0f;
  hp = ((unsigned int)__builtin_bit_cast(unsigned short, h1) << 16) |
       (unsigned int)__builtin_bit_cast(unsigned short, h0);
  lp = ((unsigned int)f16bits(l1f) << 16) | (unsigned int)f16bits(l0f);
}

static __device__ inline void split8(const float* p, half8& hi, half8& lo) {
  float4 f0 = *(const float4*)p;
  float4 f1 = *(const float4*)(p + 4);
  float fv[8] = {f0.x, f0.y, f0.z, f0.w, f1.x, f1.y, f1.z, f1.w};
#pragma unroll
  for (int j = 0; j < 8; ++j) {
    _Float16 hj = (_Float16)fv[j];
    hi[j] = hj;
    lo[j] = (_Float16)((fv[j] - (float)hj) * 2048.0f);
  }
}

// ---------------------------------------------------------------------------
// Kernel 1 (16-wave blocks): each wave owns 16 k|v rows -> A-fragments
// 32 VGPR, acc 16, one P tile-job per wave (4 heads x 2x2 tiles = 16 jobs).
// Regs ~110 -> 16 waves/CU (2x occupancy vs 4-wave version).
// grid = B_*32 = 256 blocks (1/CU), block = 1024. 2 barriers/chunk.
// ---------------------------------------------------------------------------
__global__ __launch_bounds__(1024, 4) void lin_attn_ctx(
    const float* __restrict__ x, const float* __restrict__ wqkv,
    float* __restrict__ Ws)
{
  __shared__ __align__(16) unsigned int xhiu[32 * XU_STRIDE];
  __shared__ __align__(16) unsigned int xlou[32 * XU_STRIDE];
  __shared__ __align__(16) float ks[128 * KV_STRIDE];
  __shared__ __align__(16) float vs[128 * KV_STRIDE];

  const int t = threadIdx.x;
  const int bpb = gridDim.x / B_;        // 32
  const int b = blockIdx.x / bpb;
  const int blk = blockIdx.x - b * bpb;
  const int nchunks = 512 / bpb;         // 16
  const int pbase = blk * (nchunks << 5);

  const int lane = t & 63;
  const int wave = t >> 6;               // 0..15; waves 0-7: k, 8-15: v
  const int l15 = lane & 15;
  const int quad = lane >> 4;

  // persistent A fragments: wqkv row 128 + 16*wave + l15 (k|v rows)
  half8 ahi[4], alo[4];
#pragma unroll
  for (int s = 0; s < 4; ++s)
    split8(wqkv + (size_t)(128 + (wave << 4) + l15) * C_ + (s << 5) + (quad << 3),
           ahi[s], alo[s]);

  // P tile-job for this wave: head hj, row-tile at, col-tile bt
  const int hj = wave >> 2;
  const int at = (wave >> 1) & 1;
  const int bt = wave & 1;
  floatx4 pacc1 = (floatx4){0.f, 0.f, 0.f, 0.f};
  floatx4 pacc2 = (floatx4){0.f, 0.f, 0.f, 0.f};
  float sacc[4] = {0.f, 0.f, 0.f, 0.f};

  const float* xb = x + ((size_t)b * C_) * N_;
  const int kp0 = t >> 4;            // 0..63 (channel-pair index)
  const int pq0 = (t & 15) << 1;     // 0,2,..,30 (pixel base)

  // register prefetch of chunk 0: rows 2*kp0, 2*kp0+1, cols [pq0, pq0+2)
  float2 fa0, fa1;
  {
    const float* p = xb + pbase + pq0;
    fa0 = *(const float2*)(p + (size_t)(2 * kp0) * N_);
    fa1 = *(const float2*)(p + (size_t)(2 * kp0 + 1) * N_);
  }

  for (int c4 = 0; c4 < nchunks; ++c4) {
    __syncthreads();   // A: exp-writes(i-1) -> P-reads(i-1); GEMM(i-1) -> stage(i)

    // ---- P fragment reads for PREVIOUS chunk (overlap with stage) ----
    half8 eh, el, vh, vl;
    if (c4 > 0) {
      split8(&ks[((hj << 5) + (at << 4) + l15) * KV_STRIDE + (quad << 3)], eh, el);
      split8(&vs[((hj << 5) + (bt << 4) + l15) * KV_STRIDE + (quad << 3)], vh, vl);
    }

    // ---- stage x chunk (from prefetched regs) as packed f16 hi/lo ----
    {
      float a0[2] = {fa0.x, fa0.y};
      float a1[2] = {fa1.x, fa1.y};
#pragma unroll
      for (int j = 0; j < 2; ++j) {
        unsigned int hp, lp;
        pack2(a0[j], a1[j], hp, lp);
        xhiu[(pq0 + j) * XU_STRIDE + kp0] = hp;
        xlou[(pq0 + j) * XU_STRIDE + kp0] = lp;
      }
    }

    if (c4 > 0) {
      pacc1 = __builtin_amdgcn_mfma_f32_16x16x32_f16(eh, vh, pacc1, 0, 0, 0);
      pacc2 = __builtin_amdgcn_mfma_f32_16x16x32_f16(eh, vl, pacc2, 0, 0, 0);
      pacc2 = __builtin_amdgcn_mfma_f32_16x16x32_f16(el, vh, pacc2, 0, 0, 0);
    }

    __syncthreads();   // B: stage(i) -> GEMM(i); P-reads(i-1) -> exp-writes(i)

    // prefetch next chunk; latency hides under GEMM
    if (c4 + 1 < nchunks) {
      const float* p = xb + pbase + ((c4 + 1) << 5) + pq0;
      fa0 = *(const float2*)(p + (size_t)(2 * kp0) * N_);
      fa1 = *(const float2*)(p + (size_t)(2 * kp0 + 1) * N_);
    }

    // ---- main k/v GEMM: 16 rows x 32 px per wave ----
    floatx4 acc1[2], acc2[2];
#pragma unroll
    for (int c = 0; c < 2; ++c) {
      acc1[c] = (floatx4){0.f, 0.f, 0.f, 0.f};
      acc2[c] = (floatx4){0.f, 0.f, 0.f, 0.f};
    }
    __builtin_amdgcn_s_setprio(1);
#pragma unroll
    for (int s = 0; s < 4; ++s) {
#pragma unroll
      for (int c = 0; c < 2; ++c) {
        int off = ((c << 4) + l15) * XU_STRIDE + (s << 4) + (quad << 2);
        half8 bh = __builtin_bit_cast(half8, *(const uint4*)&xhiu[off]);
        half8 bl = __builtin_bit_cast(half8, *(const uint4*)&xlou[off]);
        acc1[c] = __builtin_amdgcn_mfma_f32_16x16x32_f16(ahi[s], bh, acc1[c], 0, 0, 0);
        acc2[c] = __builtin_amdgcn_mfma_f32_16x16x32_f16(ahi[s], bl, acc2[c], 0, 0, 0);
        acc2[c] = __builtin_amdgcn_mfma_f32_16x16x32_f16(alo[s], bh, acc2[c], 0, 0, 0);
      }
    }
    __builtin_amdgcn_s_setprio(0);

    // ---- write exp(k) | v to LDS; accumulate S in registers (k waves) ----
    if (wave < 8) {
#pragma unroll
      for (int c = 0; c < 2; ++c) {
        int px = (c << 4) + l15;
#pragma unroll
        for (int reg = 0; reg < 4; ++reg) {
          float val = acc1[c][reg] + acc2[c][reg] * (1.0f / 2048.0f);
          int row = (wave << 4) + (quad << 2) + reg;       // 0..127
          float e = __expf(val);
          ks[row * KV_STRIDE + px] = e;
          sacc[reg] += e;
        }
      }
    } else {
#pragma unroll
      for (int c = 0; c < 2; ++c) {
        int px = (c << 4) + l15;
#pragma unroll
        for (int reg = 0; reg < 4; ++reg) {
          float val = acc1[c][reg] + acc2[c][reg] * (1.0f / 2048.0f);
          int row = ((wave - 8) << 4) + (quad << 2) + reg; // 0..127
          vs[row * KV_STRIDE + px] = val;
        }
      }
    }
  }

  // ---- final P update for last chunk ----
  __syncthreads();
  {
    half8 eh, el, vh, vl;
    split8(&ks[((hj << 5) + (at << 4) + l15) * KV_STRIDE + (quad << 3)], eh, el);
    split8(&vs[((hj << 5) + (bt << 4) + l15) * KV_STRIDE + (quad << 3)], vh, vl);
    pacc1 = __builtin_amdgcn_mfma_f32_16x16x32_f16(eh, vh, pacc1, 0, 0, 0);
    pacc2 = __builtin_amdgcn_mfma_f32_16x16x32_f16(eh, vl, pacc2, 0, 0, 0);
    pacc2 = __builtin_amdgcn_mfma_f32_16x16x32_f16(el, vh, pacc2, 0, 0, 0);
  }

  // ---- epilogue: per-block record {P[4096], S[128]} ----
  {
    float* rec = Ws + (size_t)blockIdx.x * REC_;
#pragma unroll
    for (int reg = 0; reg < 4; ++reg) {
      int dk = (at << 4) + (quad << 2) + reg;
      int dv = (bt << 4) + l15;
      rec[(((hj << 5) + dk) << 5) + dv] =
          pacc1[reg] + pacc2[reg] * (1.0f / 2048.0f);
    }
    if (wave < 8) {
#pragma unroll
      for (int reg = 0; reg < 4; ++reg) {
        float s = sacc[reg];
        s += __shfl_xor(s, 1);
        s += __shfl_xor(s, 2);
        s += __shfl_xor(s, 4);
        s += __shfl_xor(s, 8);
        sacc[reg] = s;
      }
      if (l15 == 0) {
#pragma unroll
        for (int reg = 0; reg < 4; ++reg)
          rec[4096 + (wave << 4) + (quad << 2) + reg] = sacc[reg];
      }
    }
  }
}

// ---------------------------------------------------------------------------
// Fused reduce+gmat (UNCHANGED): grid = B_*32, block = 256
// ---------------------------------------------------------------------------
__global__ void lin_attn_redg(const float* __restrict__ Ws, int slots,
                              const float* __restrict__ wout,
                              float* __restrict__ G)
{
  __shared__ float p2[256];
  __shared__ float cx[128];
  __shared__ float ss[4];

  const int t = threadIdx.x;
  const int b = blockIdx.x >> 5;
  const int seg = blockIdx.x & 31;
  const int R0 = seg << 2;
  const int hs = slots >> 1;

  {
    const int e = t & 127;
    const int half = t >> 7;
    const float* src = Ws + ((size_t)b * slots + (size_t)half * hs) * REC_ +
                       R0 * 32 + e;
    float s = 0.f;
    for (int k = 0; k < hs; ++k) s += src[(size_t)k * REC_];
    p2[half * 128 + e] = s;
  }
  {
    const int row4 = t >> 6;
    const int lane = t & 63;
    float sv = (lane < slots)
             ? Ws[((size_t)b * slots + lane) * REC_ + 4096 + R0 + row4] : 0.f;
    sv += __shfl_xor(sv, 1);
    sv += __shfl_xor(sv, 2);
    sv += __shfl_xor(sv, 4);
    sv += __shfl_xor(sv, 8);
    sv += __shfl_xor(sv, 16);
    sv += __shfl_xor(sv, 32);
    if (lane == 0) ss[row4] = sv;
  }
  __syncthreads();
  if (t < 128) {
    cx[t] = (p2[t] + p2[128 + t]) / (ss[t >> 5] * 16384.f);
  }
  __syncthreads();
  {
    const int o = t >> 1;
    const int pr = t & 1;
#pragma unroll
    for (int p = 0; p < 2; ++p) {
      const int row4 = pr * 2 + p;
      const int grow = R0 + row4;
      const int h = grow >> 5;
      const float* wrow = wout + (size_t)o * 128 + h * 32;
      const float* crow = &cx[row4 * 32];
      float s = 0.f;
#pragma unroll
      for (int q = 0; q < 8; ++q) {
        float4 w4 = *(const float4*)&wrow[q * 4];
        float4 c4 = *(const float4*)&crow[q * 4];
        s += w4.x * c4.x + w4.y * c4.y + w4.z * c4.z + w4.w * c4.w;
      }
      G[(size_t)b * 16384 + (size_t)o * 128 + grow] = s * SCALE_;
    }
  }
}

// ---------------------------------------------------------------------------
// Kernel 2 (UNCHANGED from round 6): 2 barriers/chunk, deferred LayerNorm.
// grid = B_*bpb, block = 256
// ---------------------------------------------------------------------------
__global__ __launch_bounds__(256, 2) void lin_attn_out(
    const float* __restrict__ x, const float* __restrict__ wqkv,
    const float* __restrict__ G, const float* __restrict__ bout,
    const float* __restrict__ alpha, const float* __restrict__ beta,
    float* __restrict__ out)
{
  __shared__ __align__(16) unsigned int xh[2][32 * XU_STRIDE];
  __shared__ __align__(16) unsigned int xl[2][32 * XU_STRIDE];
  __shared__ __align__(16) unsigned int qhiu[32 * XU_STRIDE];
  __shared__ __align__(16) unsigned int qlou[32 * XU_STRIDE];
  __shared__ float red_s[128];
  __shared__ float red_q[128];

  const int t = threadIdx.x;
  const int bpb = gridDim.x / B_;
  const int b = blockIdx.x / bpb;
  const int blk = blockIdx.x - b * bpb;
  const int nchunks = 512 / bpb;
  const int pbase = blk * (nchunks << 5);

  const int lane = t & 63;
  const int wave = t >> 6;
  const int l15 = lane & 15;
  const int quad = lane >> 4;

  half8 qhiA[2][4], qloA[2][4], ghiA[2][4], gloA[2][4];
#pragma unroll
  for (int r = 0; r < 2; ++r) {
#pragma unroll
    for (int s = 0; s < 4; ++s) {
      const int m = (wave << 5) + (r << 4) + l15;
      split8(wqkv + (size_t)m * C_ + (s << 5) + (quad << 3), qhiA[r][s], qloA[r][s]);
      split8(G + (size_t)b * 16384 + (size_t)m * 128 + (s << 5) + (quad << 3),
             ghiA[r][s], gloA[r][s]);
    }
  }

  float bch[8], ach[8], bech[8];
#pragma unroll
  for (int r = 0; r < 2; ++r)
#pragma unroll
    for (int reg = 0; reg < 4; ++reg) {
      int ch = (wave << 5) + (r << 4) + (quad << 2) + reg;
      bch[r * 4 + reg] = bout[ch];
      ach[r * 4 + reg] = alpha[ch];
      bech[r * 4 + reg] = beta[ch];
    }

  const float* xb = x + ((size_t)b * C_) * N_;
  const int kp0 = t >> 3;
  const int pq0 = (t & 7) << 2;
  float4 fa0, fa1, fb0, fb1;

  {
    const float* p = xb + pbase + pq0;
    fa0 = *(const float4*)(p + (size_t)(2 * kp0) * N_);
    fa1 = *(const float4*)(p + (size_t)(2 * kp0 + 1) * N_);
    fb0 = *(const float4*)(p + (size_t)(2 * kp0 + 64) * N_);
    fb1 = *(const float4*)(p + (size_t)(2 * kp0 + 65) * N_);
    float a0[4] = {fa0.x, fa0.y, fa0.z, fa0.w};
    float a1[4] = {fa1.x, fa1.y, fa1.z, fa1.w};
    float c0[4] = {fb0.x, fb0.y, fb0.z, fb0.w};
    float c1[4] = {fb1.x, fb1.y, fb1.z, fb1.w};
#pragma unroll
    for (int j = 0; j < 4; ++j) {
      unsigned int hp, lp;
      pack2(a0[j], a1[j], hp, lp);
      xh[0][(pq0 + j) * XU_STRIDE + kp0] = hp;
      xl[0][(pq0 + j) * XU_STRIDE + kp0] = lp;
      pack2(c0[j], c1[j], hp, lp);
      xh[0][(pq0 + j) * XU_STRIDE + kp0 + 32] = hp;
      xl[0][(pq0 + j) * XU_STRIDE + kp0 + 32] = lp;
    }
  }
  __syncthreads();

  float yv[2][8];

  for (int c4 = 0; c4 < nchunks; ++c4) {
    const int cur = c4 & 1;
    const int nxt = cur ^ 1;

    if (c4 + 1 < nchunks) {
      const float* p = xb + pbase + ((c4 + 1) << 5) + pq0;
      fa0 = *(const float4*)(p + (size_t)(2 * kp0) * N_);
      fa1 = *(const float4*)(p + (size_t)(2 * kp0 + 1) * N_);
      fb0 = *(const float4*)(p + (size_t)(2 * kp0 + 64) * N_);
      fb1 = *(const float4*)(p + (size_t)(2 * kp0 + 65) * N_);
    }

    // ---- q GEMM from xh[cur] ----
    floatx4 a1a[2][2], a2a[2][2];
#pragma unroll
    for (int r = 0; r < 2; ++r)
#pragma unroll
      for (int c = 0; c < 2; ++c) {
        a1a[r][c] = (floatx4){0.f, 0.f, 0.f, 0.f};
        a2a[r][c] = (floatx4){0.f, 0.f, 0.f, 0.f};
      }
    __builtin_amdgcn_s_setprio(1);
#pragma unroll
    for (int s = 0; s < 4; ++s) {
#pragma unroll
      for (int c = 0; c < 2; ++c) {
        int off = ((c << 4) + l15) * XU_STRIDE + (s << 4) + (quad << 2);
        half8 bh = __builtin_bit_cast(half8, *(const uint4*)&xh[cur][off]);
        half8 bl = __builtin_bit_cast(half8, *(const uint4*)&xl[cur][off]);
#pragma unroll
        for (int r = 0; r < 2; ++r) {
          a1a[r][c] = __builtin_amdgcn_mfma_f32_16x16x32_f16(qhiA[r][s], bh, a1a[r][c], 0, 0, 0);
          a2a[r][c] = __builtin_amdgcn_mfma_f32_16x16x32_f16(qhiA[r][s], bl, a2a[r][c], 0, 0, 0);
          a2a[r][c] = __builtin_amdgcn_mfma_f32_16x16x32_f16(qloA[r][s], bh, a2a[r][c], 0, 0, 0);
        }
      }
    }
    __builtin_amdgcn_s_setprio(0);

    // ---- in-register head softmax ----
    float eq[2][8];
#pragma unroll
    for (int c = 0; c < 2; ++c) {
      float qv[8];
#pragma unroll
      for (int r = 0; r < 2; ++r)
#pragma unroll
        for (int reg = 0; reg < 4; ++reg)
          qv[r * 4 + reg] = a1a[r][c][reg] + a2a[r][c][reg] * (1.0f / 2048.0f);
      float mx = fmaxf(fmaxf(fmaxf(qv[0], qv[1]), fmaxf(qv[2], qv[3])),
                       fmaxf(fmaxf(qv[4], qv[5]), fmaxf(qv[6], qv[7])));
      mx = fmaxf(mx, __shfl_xor(mx, 16));
      mx = fmaxf(mx, __shfl_xor(mx, 32));
      float ss = 0.f;
#pragma unroll
      for (int j = 0; j < 8; ++j) { eq[c][j] = __expf(qv[j] - mx); ss += eq[c][j]; }
      ss += __shfl_xor(ss, 16);
      ss += __shfl_xor(ss, 32);
      float inv = 1.0f / ss;
#pragma unroll
      for (int j = 0; j < 8; ++j) eq[c][j] *= inv;
    }
    __syncthreads();   // alpha

    // ---- deferred LN-final + store for PREVIOUS chunk ----
    if (c4 > 0) {
      float* ob = out + ((size_t)b * C_) * N_ + pbase + ((c4 - 1) << 5);
#pragma unroll
      for (int c = 0; c < 2; ++c) {
        int px = (c << 4) + l15;
        float ts = red_s[px] + red_s[32 + px] + red_s[64 + px] + red_s[96 + px];
        float tq = red_q[px] + red_q[32 + px] + red_q[64 + px] + red_q[96 + px];
        float mean = ts * (1.f / 128.f);
        float var = tq * (1.f / 128.f) - mean * mean;
        float rstd = 1.f / sqrtf(var + EPS_);
#pragma unroll
        for (int r = 0; r < 2; ++r)
#pragma unroll
          for (int reg = 0; reg < 4; ++reg) {
            int ch = (wave << 5) + (r << 4) + (quad << 2) + reg;
            ob[(size_t)ch * N_ + px] =
                (yv[c][r * 4 + reg] - mean) * rstd * ach[r * 4 + reg] + bech[r * 4 + reg];
          }
      }
    }

    // ---- emit qhat ----
#pragma unroll
    for (int c = 0; c < 2; ++c) {
      int px = (c << 4) + l15;
#pragma unroll
      for (int r = 0; r < 2; ++r) {
        unsigned int h0, l0, h1, l1;
        pack2(eq[c][r * 4 + 0], eq[c][r * 4 + 1], h0, l0);
        pack2(eq[c][r * 4 + 2], eq[c][r * 4 + 3], h1, l1);
        int kp = (wave << 4) + (r << 3) + (quad << 1);
        uint2 hu; hu.x = h0; hu.y = h1;
        uint2 lu; lu.x = l0; lu.y = l1;
        *(uint2*)&qhiu[px * XU_STRIDE + kp] = hu;
        *(uint2*)&qlou[px * XU_STRIDE + kp] = lu;
      }
    }
    // ---- stage next chunk into xh[nxt] ----
    if (c4 + 1 < nchunks) {
      float a0[4] = {fa0.x, fa0.y, fa0.z, fa0.w};
      float a1[4] = {fa1.x, fa1.y, fa1.z, fa1.w};
      float c0[4] = {fb0.x, fb0.y, fb0.z, fb0.w};
      float c1[4] = {fb1.x, fb1.y, fb1.z, fb1.w};
#pragma unroll
      for (int j = 0; j < 4; ++j) {
        unsigned int hp, lp;
        pack2(a0[j], a1[j], hp, lp);
        xh[nxt][(pq0 + j) * XU_STRIDE + kp0] = hp;
        xl[nxt][(pq0 + j) * XU_STRIDE + kp0] = lp;
        pack2(c0[j], c1[j], hp, lp);
        xh[nxt][(pq0 + j) * XU_STRIDE + kp0 + 32] = hp;
        xl[nxt][(pq0 + j) * XU_STRIDE + kp0 + 32] = lp;
      }
    }
    __syncthreads();   // beta

    // ---- y GEMM: y = G * qhat ----
#pragma unroll
    for (int r = 0; r < 2; ++r)
#pragma unroll
      for (int c = 0; c < 2; ++c) {
        a1a[r][c] = (floatx4){0.f, 0.f, 0.f, 0.f};
        a2a[r][c] = (floatx4){0.f, 0.f, 0.f, 0.f};
      }
    __builtin_amdgcn_s_setprio(1);
#pragma unroll
    for (int s = 0; s < 4; ++s) {
#pragma unroll
      for (int c = 0; c < 2; ++c) {
        int off = ((c << 4) + l15) * XU_STRIDE + (s << 4) + (quad << 2);
        half8 bh = __builtin_bit_cast(half8, *(const uint4*)&qhiu[off]);
        half8 bl = __builtin_bit_cast(half8, *(const uint4*)&qlou[off]);
#pragma unroll
        for (int r = 0; r < 2; ++r) {
          a1a[r][c] = __builtin_amdgcn_mfma_f32_16x16x32_f16(ghiA[r][s], bh, a1a[r][c], 0, 0, 0);
          a2a[r][c] = __builtin_amdgcn_mfma_f32_16x16x32_f16(ghiA[r][s], bl, a2a[r][c], 0, 0, 0);
          a2a[r][c] = __builtin_amdgcn_mfma_f32_16x16x32_f16(gloA[r][s], bh, a2a[r][c], 0, 0, 0);
        }
      }
    }
    __builtin_amdgcn_s_setprio(0);

    // ---- y + bias into yv; LayerNorm partials ----
#pragma unroll
    for (int c = 0; c < 2; ++c) {
      float sm = 0.f, sq = 0.f;
#pragma unroll
      for (int r = 0; r < 2; ++r)
#pragma unroll
        for (int reg = 0; reg < 4; ++reg) {
          float v = a1a[r][c][reg] + a2a[r][c][reg] * (1.0f / 2048.0f) + bch[r * 4 + reg];
          yv[c][r * 4 + reg] = v;
          sm += v;
          sq += v * v;
        }
      sm += __shfl_xor(sm, 16);  sq += __shfl_xor(sq, 16);
      sm += __shfl_xor(sm, 32);  sq += __shfl_xor(sq, 32);
      if (quad == 0) {
        red_s[(wave << 5) + (c << 4) + l15] = sm;
        red_q[(wave << 5) + (c << 4) + l15] = sq;
      }
    }
  }

  // ---- epilogue: LN-final + store for the last chunk ----
  __syncthreads();
  {
    float* ob = out + ((size_t)b * C_) * N_ + pbase + ((nchunks - 1) << 5);
#pragma unroll
    for (int c = 0; c < 2; ++c) {
      int px = (c << 4) + l15;
      float ts = red_s[px] + red_s[32 + px] + red_s[64 + px] + red_s[96 + px];
      float tq = red_q[px] + red_q[32 + px] + red_q[64 + px] + red_q[96 + px];
      float mean = ts * (1.f / 128.f);
      float var = tq * (1.f / 128.f) - mean * mean;
      float rstd = 1.f / sqrtf(var + EPS_);
#pragma unroll
      for (int r = 0; r < 2; ++r)
#pragma unroll
        for (int reg = 0; reg < 4; ++reg) {
          int ch = (wave << 5) + (r << 4) + (quad << 2) + reg;
          ob[(size_t)ch * N_ + px] =
              (yv[c][r * 4 + reg] - mean) * rstd * ach[r * 4 + reg] + bech[r * 4 + reg];
        }
    }
  }
}

extern "C" void kernel_launch(void* const* d_in, const int* in_sizes, int n_in,
                              void* d_out, int out_size, void* d_ws, size_t ws_size,
                              hipStream_t stream) {
  const float* x     = (const float*)d_in[0];
  const float* wqkv  = (const float*)d_in[1];
  const float* wout  = (const float*)d_in[2];
  const float* bout  = (const float*)d_in[3];
  const float* alpha = (const float*)d_in[4];
  const float* beta  = (const float*)d_in[5];
  float* outp = (float*)d_out;

  // workspace layout: G | (reserved) | records
  float* G  = (float*)d_ws;                          // [B][128][128]
  float* Ws = G + (size_t)B_ * 16384 + B_ * 4096 + B_ * 128;

  const int bpb_ctx = 32;   // 256 blocks of 1024 threads = 1 block/CU

  lin_attn_ctx<<<dim3(B_ * bpb_ctx), dim3(1024), 0, stream>>>(x, wqkv, Ws);
  lin_attn_redg<<<dim3(B_ * 32), dim3(256), 0, stream>>>(Ws, bpb_ctx, wout, G);
  lin_attn_out<<<dim3(B_ * 64), dim3(256), 0, stream>>>(x, wqkv, G, bout,
                                                        alpha, beta, outp);
}